// Round 12
// baseline (142.821 us; speedup 1.0000x reference)
//
#include <hip/hip_runtime.h>
#include <math.h>

// B=4, S=2048, D=512, H=8, A=O=64.
// prep: x f32 -> xh f16; W -> W^T f16.
// qkv_gemm (r6-exact): 128x64 tiles, grid (64 m,17 n) -> XCD = m%8.
//   Double-buffered single-barrier staging. 48KB LDS, 3 blocks/CU.
// K and V^T stored as swizzled 64x64 f16 tiles (8KB):
//   (row,col) at halves offset row*64 + (((col>>3) ^ (row&7))<<3) + (col&7)
// attn v3: LDS-BW fix. Per-trip LDS reads were 18KB/wave with 4 waves/group
//   all reading the SAME 8KB K/V tiles (4x amplification) -> ~288KB/CU/trip,
//   ~8x oversubscribed vs MFMA. Now each wave computes 32 q-rows (two 16-row
//   blocks, qkv's s-loop pattern): K/V fragments read once, used twice ->
//   80KB/block-trip (-44%). Block = 4 waves = 256 thr; 2-wave anti-phase
//   groups (r6 schedule); grid (32 bh, 32 p), p = 31-y (r11's balanced
//   permutation was noise -> reverted). 80KB LDS, 2 blocks/CU.

typedef _Float16 half8 __attribute__((ext_vector_type(8)));
typedef _Float16 half4 __attribute__((ext_vector_type(4)));
typedef float float4v __attribute__((ext_vector_type(4)));
typedef unsigned int u32;

#define SCL2E 0.031885926f   // (1/sqrt(2048)) * log2(e)

__device__ inline float4v mfma16(half8 a, half8 b, float4v c) {
    return __builtin_amdgcn_mfma_f32_16x16x32_f16(a, b, c, 0, 0, 0);
}
__device__ inline void load16(const _Float16* g, _Float16* l) {
    __builtin_amdgcn_global_load_lds((const __attribute__((address_space(1))) u32*)g,
                                     (__attribute__((address_space(3))) u32*)l, 16, 0, 0);
}

// ---------------- prep: x -> f16, W -> W^T f16 (one launch) ----------------
__global__ __launch_bounds__(256) void prep(
    const float* __restrict__ x, const float* __restrict__ Wq,
    const float* __restrict__ Wk, const float* __restrict__ Wv,
    _Float16* __restrict__ xh, _Float16* __restrict__ wqt,
    _Float16* __restrict__ wkt, _Float16* __restrict__ wvt) {
    const int bid = blockIdx.x;
    if (bid < 2048) {
        size_t base = (size_t)bid * 2048 + (size_t)threadIdx.x * 8;
        const float4* xp = (const float4*)(x + base);
        float4 f0 = xp[0], f1 = xp[1];
        half8 h = {(_Float16)f0.x, (_Float16)f0.y, (_Float16)f0.z, (_Float16)f0.w,
                   (_Float16)f1.x, (_Float16)f1.y, (_Float16)f1.z, (_Float16)f1.w};
        *(half8*)(xh + base) = h;
    } else {
        int r = bid - 2048;
        const float* W; _Float16* WT; int N, bx, by;
        if (r < 256)      { W = Wq; WT = wqt; N = 512; bx = r & 15; by = r >> 4; }
        else if (r < 288) { r -= 256; W = Wk; WT = wkt; N = 64;  bx = r & 1;  by = r >> 1; }
        else              { r -= 288; W = Wv; WT = wvt; N = 512; bx = r & 15; by = r >> 4; }
        __shared__ float T[32][33];
        const int tx = threadIdx.x & 31, ty = threadIdx.x >> 5;
        const int n0 = bx * 32, k0 = by * 32;
#pragma unroll
        for (int i = 0; i < 4; ++i)
            T[ty + 8 * i][tx] = W[(size_t)(k0 + ty + 8 * i) * N + n0 + tx];
        __syncthreads();
#pragma unroll
        for (int i = 0; i < 4; ++i)
            WT[(size_t)(n0 + ty + 8 * i) * 512 + k0 + tx] = (_Float16)T[tx][ty + 8 * i];
    }
}

// ---------------- fused QKV GEMM (r6-exact) ----------------
// grid (64, 17): x = m-tile (128 rows) -> XCD = m%8; y = n-tile (0..7 q, 8 k, 9..16 v).
__global__ __launch_bounds__(256) void qkv_gemm(
    const _Float16* __restrict__ xh,
    const _Float16* __restrict__ wqt, const _Float16* __restrict__ wkt,
    const _Float16* __restrict__ wvt,
    const float* __restrict__ bq, const float* __restrict__ bv,
    _Float16* __restrict__ q_ws, _Float16* __restrict__ kt_ws, _Float16* __restrict__ vt_ws) {
    __shared__ __align__(16) _Float16 Xs[2][8192];   // 2 x 128x64 (swizzled) = 32KB
    __shared__ __align__(16) _Float16 Ws[2][4096];   // 2 x 64x64  (swizzled) = 16KB

    const int m0 = blockIdx.x * 128;
    const int nt = blockIdx.y;
    const _Float16* WT;
    const float* bias;
    if (nt < 8)       { WT = wqt + (size_t)nt * 64 * 512; bias = bq + nt * 64; }
    else if (nt == 8) { WT = wkt;                          bias = nullptr; }
    else              { WT = wvt + (size_t)(nt - 9) * 64 * 512; bias = bv + (nt - 9) * 64; }

    const int tid = threadIdx.x;
    const int w = tid >> 6, lane = tid & 63, quad = lane >> 4, cl = lane & 15;
    const int lrow = lane >> 3;                  // 0..7
    const int lgc = (lane & 7) ^ lrow;           // swizzled source granule
    const _Float16* xg = xh + (size_t)(m0 + lrow) * 512 + lgc * 8;
    const _Float16* wg = WT + (size_t)lrow * 512 + lgc * 8;

    const int g0 = (quad ^ (cl & 7)) << 3;
    const int g1 = ((quad ^ 4) ^ (cl & 7)) << 3;

    float4v acc[2][4] = {};

    // prologue: stage K-step 0 into buffer 0
#pragma unroll
    for (int c = 0; c < 4; ++c) {
        int cc = w * 4 + c;
        load16(xg + (size_t)cc * 8 * 512, Xs[0] + cc * 512);
    }
#pragma unroll
    for (int c = 0; c < 2; ++c) {
        int cc = w * 2 + c;
        load16(wg + (size_t)cc * 8 * 512, Ws[0] + cc * 512);
    }

    for (int ki = 0; ki < 8; ++ki) {
        const int cb = ki & 1, nb = cb ^ 1;
        __syncthreads();   // buf[cb] staged (vmcnt drain); buf[nb] reads done
        if (ki < 7) {
            const int kk = (ki + 1) * 64;
#pragma unroll
            for (int c = 0; c < 4; ++c) {
                int cc = w * 4 + c;
                load16(xg + (size_t)cc * 8 * 512 + kk, Xs[nb] + cc * 512);
            }
#pragma unroll
            for (int c = 0; c < 2; ++c) {
                int cc = w * 2 + c;
                load16(wg + (size_t)cc * 8 * 512 + kk, Ws[nb] + cc * 512);
            }
        }
#pragma unroll
        for (int c = 0; c < 2; ++c) {
            const int g = c ? g1 : g0;
#pragma unroll
            for (int s = 0; s < 2; ++s) {
                half8 a = *(const half8*)(Xs[cb] + (w * 32 + s * 16 + cl) * 64 + g);
#pragma unroll
                for (int j = 0; j < 4; ++j) {
                    half8 b = *(const half8*)(Ws[cb] + (j * 16 + cl) * 64 + g);
                    acc[s][j] = mfma16(a, b, acc[s][j]);
                }
            }
        }
    }

    if (nt < 8) {
#pragma unroll
        for (int s = 0; s < 2; ++s)
#pragma unroll
            for (int j = 0; j < 4; ++j)
#pragma unroll
                for (int r = 0; r < 4; ++r) {
                    int lr = w * 32 + s * 16 + quad * 4 + r;
                    int col = j * 16 + cl;
                    q_ws[(size_t)(m0 + lr) * 512 + nt * 64 + col] =
                        (_Float16)((acc[s][j][r] + bias[col]) * SCL2E);
                }
    } else if (nt == 8) {
#pragma unroll
        for (int s = 0; s < 2; ++s)
#pragma unroll
            for (int j = 0; j < 4; ++j)
#pragma unroll
                for (int r = 0; r < 4; ++r) {
                    int grow = m0 + w * 32 + s * 16 + quad * 4 + r;
                    int b = grow >> 11, t = (grow >> 6) & 31, row = grow & 63;
                    int col = j * 16 + cl;
                    kt_ws[((size_t)(b * 32 + t) << 12) + row * 64 +
                          (((col >> 3) ^ (row & 7)) << 3) + (col & 7)] = (_Float16)acc[s][j][r];
                }
    } else {
        const int h = nt - 9;
#pragma unroll
        for (int s = 0; s < 2; ++s)
#pragma unroll
            for (int j = 0; j < 4; ++j)
#pragma unroll
                for (int r = 0; r < 4; ++r) {
                    int grow = m0 + w * 32 + s * 16 + quad * 4 + r;
                    int b = grow >> 11, t = (grow >> 6) & 31, row = grow & 63;
                    int o = j * 16 + cl;
                    int kap = ((row & 15) << 2) + (row >> 4);
                    vt_ws[(((size_t)(b * 8 + h) * 32 + t) << 12) + o * 64 +
                          (((kap >> 3) ^ (o & 7)) << 3) + (kap & 7)] =
                        (_Float16)(acc[s][j][r] + bias[o]);
                }
    }
}

// ---------------- causal flash attention v3: 32 rows/wave ----------------
// grid (32, 32): x = bh -> XCD = bh%8; y -> p = 31-y (heavy first).
// 256 threads = 4 waves = 2 groups of 2; wave wl in group g owns q rows
// [q0+wl*32, q0+wl*32+32) via two 16-row blocks (s=0,1). K/V fragments are
// read once per wave and reused for both s -> half the LDS read traffic.
// Group g owns KV tiles [g?nmax:0, g?p+1:nmax), nmax = ceil((p+1)/2).
// Group 0: stage(t+1) -> QK(t) -> SM(t) -> PV(t).
// Group 1: PV(t-1) -> stage(K t+1, V t) -> QK(t) -> SM(t); tail PV after loop.
__global__ __launch_bounds__(256, 2) void attn(
    const _Float16* __restrict__ q_ws, const _Float16* __restrict__ kt_ws,
    const _Float16* __restrict__ vt_ws, float* __restrict__ out) {
    __shared__ __align__(16) _Float16 Ks[2][2][4096];     // [group][buf] 32KB
    __shared__ __align__(16) _Float16 VTs[2][2][4096];    // 32KB
    __shared__ __align__(16) _Float16 Ps[4][2048];        // 4 waves x 32x64 = 16KB -> 80KB

    const int bh = blockIdx.x, b = bh >> 3, h = bh & 7;
    const int p = 31 - blockIdx.y;            // q-half index, heavy first
    const int q0 = p * 64;                    // first q row of this half
    const int nmax = (p + 2) >> 1;            // ceil((p+1)/2) = uniform loop count

    const int bS = b * 2048;
    const int tid = threadIdx.x;
    const int w = tid >> 6, lane = tid & 63, quad = lane >> 4, cl = lane & 15;
    const int g = w >> 1, wl = w & 1;         // group, wave-in-group
    const int tbase = g ? nmax : 0;           // first KV tile of my group
    const int nit = g ? (p + 1 - nmax) : nmax;// my group's iteration count

    const _Float16* kbase = kt_ws + ((size_t)(b * 32) << 12);
    const _Float16* vbase = vt_ws + ((size_t)((b * 8 + h) * 32) << 12);

    const int g0 = (quad ^ (cl & 7)) << 3;
    const int g1 = ((quad ^ 4) ^ (cl & 7)) << 3;
    const int so0 = wl * 2048 + lane * 8;     // per-lane global staging offset
    const int sd0 = wl * 2048;                // wave-uniform LDS dest offset

    // Q pre-scaled by SCL2E in gemm epilogue; wave covers rows q0+wl*32 .. +31
    half8 qa[2][2];
#pragma unroll
    for (int s = 0; s < 2; ++s) {
        const _Float16* qb = q_ws + (size_t)(bS + q0 + wl * 32 + s * 16 + cl) * 512 + h * 64;
        qa[s][0] = *(const half8*)(qb + quad * 8);
        qa[s][1] = *(const half8*)(qb + 32 + quad * 8);
    }

    float4v oacc[2][4] = {};
    float l_run[2][4] = {};

    _Float16* KsG = &Ks[g][0][0];             // my group's [2][4096]
    _Float16* VsG = &VTs[g][0][0];

    auto stageK = [&](int tile, int buf) {
        const _Float16* kt = kbase + ((size_t)tile << 12);
#pragma unroll
        for (int c = 0; c < 4; ++c)
            load16(kt + so0 + c * 512, KsG + buf * 4096 + sd0 + c * 512);
    };
    auto stageV = [&](int tile, int buf) {
        const _Float16* vt = vbase + ((size_t)tile << 12);
#pragma unroll
        for (int c = 0; c < 4; ++c)
            load16(vt + so0 + c * 512, VsG + buf * 4096 + sd0 + c * 512);
    };
    auto qk_sm = [&](int tg, int buf) {
        const _Float16* KB = KsG + buf * 4096;
        if (tg != p) {
            // ---- full tile: maskless fast path; K frags shared across s ----
            float4v sfr[2][4];
#pragma unroll
            for (int j = 0; j < 4; ++j) {
                const _Float16* kr = KB + (j * 16 + cl) * 64;
                half8 b0 = *(const half8*)(kr + g0);
                half8 b1 = *(const half8*)(kr + g1);
#pragma unroll
                for (int s = 0; s < 2; ++s) {
                    float4v a_ = {0.f, 0.f, 0.f, 0.f};
                    a_ = mfma16(qa[s][0], b0, a_);
                    a_ = mfma16(qa[s][1], b1, a_);
                    sfr[s][j] = a_;
                }
            }
#pragma unroll
            for (int s = 0; s < 2; ++s)
#pragma unroll
                for (int r = 0; r < 4; ++r) {
                    float p0 = exp2f(sfr[s][0][r]), p1 = exp2f(sfr[s][1][r]);
                    float p2 = exp2f(sfr[s][2][r]), p3 = exp2f(sfr[s][3][r]);
                    l_run[s][r] += (p0 + p1) + (p2 + p3);
                    int rr = s * 16 + quad * 4 + r;
                    half4 ph = {(_Float16)p0, (_Float16)p1, (_Float16)p2, (_Float16)p3};
                    *(half4*)&Ps[w][rr * 64 + ((((cl >> 1) ^ (rr & 7)) << 3) | ((cl & 1) << 2))] = ph;
                }
        } else {
            // ---- diagonal tile: 16-row block index = wl*2+s ----
            float4v sfr[2][4];
#pragma unroll
            for (int j = 0; j < 4; ++j) {
                if (j <= wl * 2 + 1) {
                    const _Float16* kr = KB + (j * 16 + cl) * 64;
                    half8 b0 = *(const half8*)(kr + g0);
                    half8 b1 = *(const half8*)(kr + g1);
#pragma unroll
                    for (int s = 0; s < 2; ++s) {
                        if (j <= wl * 2 + s) {
                            float4v a_ = {0.f, 0.f, 0.f, 0.f};
                            a_ = mfma16(qa[s][0], b0, a_);
                            a_ = mfma16(qa[s][1], b1, a_);
                            sfr[s][j] = a_;
                        }
                    }
                }
            }
#pragma unroll
            for (int s = 0; s < 2; ++s) {
                const int jmax = wl * 2 + s;
#pragma unroll
                for (int r = 0; r < 4; ++r) {
                    float pj[4];
#pragma unroll
                    for (int j = 0; j < 4; ++j) {
                        bool live = (j < jmax) || (j == jmax && cl <= quad * 4 + r);
                        pj[j] = live ? exp2f(sfr[s][j][r]) : 0.f;
                    }
                    l_run[s][r] += (pj[0] + pj[1]) + (pj[2] + pj[3]);
                    int rr = s * 16 + quad * 4 + r;
                    half4 ph = {(_Float16)pj[0], (_Float16)pj[1], (_Float16)pj[2], (_Float16)pj[3]};
                    *(half4*)&Ps[w][rr * 64 + ((((cl >> 1) ^ (rr & 7)) << 3) | ((cl & 1) << 2))] = ph;
                }
            }
        }
    };
    auto pv = [&](int buf) {
        // Ps is per-wave: same-wave RAW through LDS, no barrier needed.
        // P rows s*16+cl: (s*16+cl)&7 == cl&7 -> same g0/g1 swizzle valid.
        const _Float16* PB0 = &Ps[w][cl * 64];
        const _Float16* PB1 = &Ps[w][(16 + cl) * 64];
        half8 pa00 = *(const half8*)(PB0 + g0);
        half8 pa01 = *(const half8*)(PB0 + g1);
        half8 pa10 = *(const half8*)(PB1 + g0);
        half8 pa11 = *(const half8*)(PB1 + g1);
        const _Float16* VB = VsG + buf * 4096;
#pragma unroll
        for (int jo = 0; jo < 4; ++jo) {
            const _Float16* vr = VB + (jo * 16 + cl) * 64;
            half8 v0 = *(const half8*)(vr + g0);
            half8 v1 = *(const half8*)(vr + g1);
            oacc[0][jo] = mfma16(pa00, v0, oacc[0][jo]);
            oacc[0][jo] = mfma16(pa01, v1, oacc[0][jo]);
            oacc[1][jo] = mfma16(pa10, v0, oacc[1][jo]);
            oacc[1][jo] = mfma16(pa11, v1, oacc[1][jo]);
        }
    };

    // prologue
    if (nit > 0) {
        stageK(tbase, 0);
        if (g == 0) stageV(tbase, 0);   // g1 stages V(t) inside trip t
    }

    for (int t = 0; t < nmax; ++t) {
        const int cb = t & 1, nb = cb ^ 1;
        __syncthreads();   // staged tiles landed (vmcnt drain); buf[nb] reads done
        const int tg = tbase + t;
        if (g == 0) {
            if (t + 1 < nit) { stageK(tg + 1, nb); stageV(tg + 1, nb); }
            qk_sm(tg, cb);
            pv(cb);
        } else {
            if (t > 0 && t - 1 < nit) pv(nb);          // PV of tile tg-1 (V in buf (t-1)&1)
            if (t + 1 < nit) stageK(tg + 1, nb);
            if (t < nit) {
                stageV(tg, cb);                         // V(t): read at trip t+1 / tail
                qk_sm(tg, cb);
            }
        }
    }

    __syncthreads();                              // all staging landed, all LDS reads done
    if (g == 1 && nit == nmax) pv((nmax - 1) & 1);   // tail PV not covered in-loop

    // ---- in-block combine: group 1 -> LDS, group 0 adds + normalizes ----
    float* Obuf = (float*)&Ks[1][0][0];           // 16KB (g1 K staging, dead)
    float* Lbuf = (float*)&VTs[0][0][0];          // 4KB of g0 V staging (dead)
    if (g == 1) {
#pragma unroll
        for (int s = 0; s < 2; ++s)
#pragma unroll
            for (int jo = 0; jo < 4; ++jo)
#pragma unroll
                for (int r = 0; r < 4; ++r) {
                    int row = wl * 32 + s * 16 + quad * 4 + r;
                    Obuf[row * 64 + jo * 16 + cl] = oacc[s][jo][r];
                }
#pragma unroll
        for (int s = 0; s < 2; ++s)
#pragma unroll
            for (int r = 0; r < 4; ++r) {
                int row = wl * 32 + s * 16 + quad * 4 + r;
                Lbuf[row * 16 + cl] = l_run[s][r];
            }
    }
    __syncthreads();
    if (g == 0) {
#pragma unroll
        for (int s = 0; s < 2; ++s)
#pragma unroll
            for (int r = 0; r < 4; ++r) {
                int row = wl * 32 + s * 16 + quad * 4 + r;
                float l = l_run[s][r] + Lbuf[row * 16 + cl];
                l += __shfl_xor(l, 1);
                l += __shfl_xor(l, 2);
                l += __shfl_xor(l, 4);
                l += __shfl_xor(l, 8);
                float inv = 1.0f / l;
                float* op = out + (size_t)(bS + q0 + row) * 512 + h * 64 + cl;
                op[0]  = (oacc[s][0][r] + Obuf[row * 64 +      cl]) * inv;
                op[16] = (oacc[s][1][r] + Obuf[row * 64 + 16 + cl]) * inv;
                op[32] = (oacc[s][2][r] + Obuf[row * 64 + 32 + cl]) * inv;
                op[48] = (oacc[s][3][r] + Obuf[row * 64 + 48 + cl]) * inv;
            }
    }
}

extern "C" void kernel_launch(void* const* d_in, const int* in_sizes, int n_in,
                              void* d_out, int out_size, void* d_ws, size_t ws_size,
                              hipStream_t stream) {
    const float* x  = (const float*)d_in[0];
    const float* Wq = (const float*)d_in[1];
    const float* bq = (const float*)d_in[2];
    const float* Wk = (const float*)d_in[3];
    const float* Wv = (const float*)d_in[4];
    const float* bv = (const float*)d_in[5];
    float* out = (float*)d_out;

    char* ws = (char*)d_ws;
    _Float16* q_ws  = (_Float16*)(ws);                 // 8192*512*2     = 8388608
    _Float16* kt_ws = (_Float16*)(ws + 8388608);       // 4*32*4096*2    = 1048576
    _Float16* vt_ws = (_Float16*)(ws + 9437184);       // 4*8*32*4096*2  = 8388608
    _Float16* wqt   = (_Float16*)(ws + 17825792);      // 512*512*2      = 524288
    _Float16* wkt   = (_Float16*)(ws + 18350080);      // 64*512*2       = 65536
    _Float16* wvt   = (_Float16*)(ws + 18415616);      // 512*512*2      = 524288
    _Float16* xh    = (_Float16*)(ws + 18939904);      // 8192*512*2     = 8388608 -> end 27328512

    prep<<<dim3(2592), dim3(256), 0, stream>>>(x, Wq, Wk, Wv, xh, wqt, wkt, wvt);

    qkv_gemm<<<dim3(64, 17), dim3(256), 0, stream>>>(
        xh, wqt, wkt, wvt, bq, bv, q_ws, kt_ws, vt_ws);

    attn<<<dim3(32, 32), dim3(256), 0, stream>>>(q_ws, kt_ws, vt_ws, out);
}

// Round 13
// 137.716 us; speedup vs baseline: 1.0371x; 1.0371x over previous
//
#include <hip/hip_runtime.h>
#include <math.h>

// B=4, S=2048, D=512, H=8, A=O=64.
// FINAL: byte-exact revert to the best measured configuration (r6, 139.97us).
// prep: x f32 -> xh f16; W -> W^T f16.
// qkv_gemm: 128x64 tiles, grid (64 m,17 n) -> XCD = m%8. Double-buffered
//   single-barrier staging: per K-iter: bar -> issue next tile -> MFMA. 48KB LDS.
//   (r7/r9: both 128x128 variants regress; this is the measured optimum.)
// K and V^T stored as swizzled 64x64 f16 tiles (8KB):
//   (row,col) at halves offset row*64 + (((col>>3) ^ (row&7))<<3) + (col&7)
// attn: grid (32 bh, 32 p) of 512-thr blocks; anti-phase 2-group KV split.
//   Group 0: stage(t+1) -> QK(t) -> SM(t) -> PV(t).
//   Group 1: PV(t-1) -> stage(K t+1, V t) -> QK(t) -> SM(t); tail PV after.
//   p = 31-y heavy-first (r11: exact-balance permutation = noise);
//   4-wave groups (r12: 2-wave/32-row variant regressed, +bank conflicts).
//   80KB LDS, 2 blocks/CU. XCD = bh%8 -> KV L2-resident.

typedef _Float16 half8 __attribute__((ext_vector_type(8)));
typedef _Float16 half4 __attribute__((ext_vector_type(4)));
typedef float float4v __attribute__((ext_vector_type(4)));
typedef unsigned int u32;

#define SCL2E 0.031885926f   // (1/sqrt(2048)) * log2(e)

__device__ inline float4v mfma16(half8 a, half8 b, float4v c) {
    return __builtin_amdgcn_mfma_f32_16x16x32_f16(a, b, c, 0, 0, 0);
}
__device__ inline void load16(const _Float16* g, _Float16* l) {
    __builtin_amdgcn_global_load_lds((const __attribute__((address_space(1))) u32*)g,
                                     (__attribute__((address_space(3))) u32*)l, 16, 0, 0);
}

// ---------------- prep: x -> f16, W -> W^T f16 (one launch) ----------------
__global__ __launch_bounds__(256) void prep(
    const float* __restrict__ x, const float* __restrict__ Wq,
    const float* __restrict__ Wk, const float* __restrict__ Wv,
    _Float16* __restrict__ xh, _Float16* __restrict__ wqt,
    _Float16* __restrict__ wkt, _Float16* __restrict__ wvt) {
    const int bid = blockIdx.x;
    if (bid < 2048) {
        size_t base = (size_t)bid * 2048 + (size_t)threadIdx.x * 8;
        const float4* xp = (const float4*)(x + base);
        float4 f0 = xp[0], f1 = xp[1];
        half8 h = {(_Float16)f0.x, (_Float16)f0.y, (_Float16)f0.z, (_Float16)f0.w,
                   (_Float16)f1.x, (_Float16)f1.y, (_Float16)f1.z, (_Float16)f1.w};
        *(half8*)(xh + base) = h;
    } else {
        int r = bid - 2048;
        const float* W; _Float16* WT; int N, bx, by;
        if (r < 256)      { W = Wq; WT = wqt; N = 512; bx = r & 15; by = r >> 4; }
        else if (r < 288) { r -= 256; W = Wk; WT = wkt; N = 64;  bx = r & 1;  by = r >> 1; }
        else              { r -= 288; W = Wv; WT = wvt; N = 512; bx = r & 15; by = r >> 4; }
        __shared__ float T[32][33];
        const int tx = threadIdx.x & 31, ty = threadIdx.x >> 5;
        const int n0 = bx * 32, k0 = by * 32;
#pragma unroll
        for (int i = 0; i < 4; ++i)
            T[ty + 8 * i][tx] = W[(size_t)(k0 + ty + 8 * i) * N + n0 + tx];
        __syncthreads();
#pragma unroll
        for (int i = 0; i < 4; ++i)
            WT[(size_t)(n0 + ty + 8 * i) * 512 + k0 + tx] = (_Float16)T[tx][ty + 8 * i];
    }
}

// ---------------- fused QKV GEMM ----------------
// grid (64, 17): x = m-tile (128 rows) -> XCD = m%8; y = n-tile (0..7 q, 8 k, 9..16 v).
__global__ __launch_bounds__(256) void qkv_gemm(
    const _Float16* __restrict__ xh,
    const _Float16* __restrict__ wqt, const _Float16* __restrict__ wkt,
    const _Float16* __restrict__ wvt,
    const float* __restrict__ bq, const float* __restrict__ bv,
    _Float16* __restrict__ q_ws, _Float16* __restrict__ kt_ws, _Float16* __restrict__ vt_ws) {
    __shared__ __align__(16) _Float16 Xs[2][8192];   // 2 x 128x64 (swizzled) = 32KB
    __shared__ __align__(16) _Float16 Ws[2][4096];   // 2 x 64x64  (swizzled) = 16KB

    const int m0 = blockIdx.x * 128;
    const int nt = blockIdx.y;
    const _Float16* WT;
    const float* bias;
    if (nt < 8)       { WT = wqt + (size_t)nt * 64 * 512; bias = bq + nt * 64; }
    else if (nt == 8) { WT = wkt;                          bias = nullptr; }
    else              { WT = wvt + (size_t)(nt - 9) * 64 * 512; bias = bv + (nt - 9) * 64; }

    const int tid = threadIdx.x;
    const int w = tid >> 6, lane = tid & 63, quad = lane >> 4, cl = lane & 15;
    const int lrow = lane >> 3;                  // 0..7
    const int lgc = (lane & 7) ^ lrow;           // swizzled source granule
    const _Float16* xg = xh + (size_t)(m0 + lrow) * 512 + lgc * 8;
    const _Float16* wg = WT + (size_t)lrow * 512 + lgc * 8;

    const int g0 = (quad ^ (cl & 7)) << 3;
    const int g1 = ((quad ^ 4) ^ (cl & 7)) << 3;

    float4v acc[2][4] = {};

    // prologue: stage K-step 0 into buffer 0
#pragma unroll
    for (int c = 0; c < 4; ++c) {
        int cc = w * 4 + c;
        load16(xg + (size_t)cc * 8 * 512, Xs[0] + cc * 512);
    }
#pragma unroll
    for (int c = 0; c < 2; ++c) {
        int cc = w * 2 + c;
        load16(wg + (size_t)cc * 8 * 512, Ws[0] + cc * 512);
    }

    for (int ki = 0; ki < 8; ++ki) {
        const int cb = ki & 1, nb = cb ^ 1;
        __syncthreads();   // buf[cb] staged (vmcnt drain); buf[nb] reads done
        if (ki < 7) {
            const int kk = (ki + 1) * 64;
#pragma unroll
            for (int c = 0; c < 4; ++c) {
                int cc = w * 4 + c;
                load16(xg + (size_t)cc * 8 * 512 + kk, Xs[nb] + cc * 512);
            }
#pragma unroll
            for (int c = 0; c < 2; ++c) {
                int cc = w * 2 + c;
                load16(wg + (size_t)cc * 8 * 512 + kk, Ws[nb] + cc * 512);
            }
        }
#pragma unroll
        for (int c = 0; c < 2; ++c) {
            const int g = c ? g1 : g0;
#pragma unroll
            for (int s = 0; s < 2; ++s) {
                half8 a = *(const half8*)(Xs[cb] + (w * 32 + s * 16 + cl) * 64 + g);
#pragma unroll
                for (int j = 0; j < 4; ++j) {
                    half8 b = *(const half8*)(Ws[cb] + (j * 16 + cl) * 64 + g);
                    acc[s][j] = mfma16(a, b, acc[s][j]);
                }
            }
        }
    }

    if (nt < 8) {
#pragma unroll
        for (int s = 0; s < 2; ++s)
#pragma unroll
            for (int j = 0; j < 4; ++j)
#pragma unroll
                for (int r = 0; r < 4; ++r) {
                    int lr = w * 32 + s * 16 + quad * 4 + r;
                    int col = j * 16 + cl;
                    q_ws[(size_t)(m0 + lr) * 512 + nt * 64 + col] =
                        (_Float16)((acc[s][j][r] + bias[col]) * SCL2E);
                }
    } else if (nt == 8) {
#pragma unroll
        for (int s = 0; s < 2; ++s)
#pragma unroll
            for (int j = 0; j < 4; ++j)
#pragma unroll
                for (int r = 0; r < 4; ++r) {
                    int grow = m0 + w * 32 + s * 16 + quad * 4 + r;
                    int b = grow >> 11, t = (grow >> 6) & 31, row = grow & 63;
                    int col = j * 16 + cl;
                    kt_ws[((size_t)(b * 32 + t) << 12) + row * 64 +
                          (((col >> 3) ^ (row & 7)) << 3) + (col & 7)] = (_Float16)acc[s][j][r];
                }
    } else {
        const int h = nt - 9;
#pragma unroll
        for (int s = 0; s < 2; ++s)
#pragma unroll
            for (int j = 0; j < 4; ++j)
#pragma unroll
                for (int r = 0; r < 4; ++r) {
                    int grow = m0 + w * 32 + s * 16 + quad * 4 + r;
                    int b = grow >> 11, t = (grow >> 6) & 31, row = grow & 63;
                    int o = j * 16 + cl;
                    int kap = ((row & 15) << 2) + (row >> 4);
                    vt_ws[(((size_t)(b * 8 + h) * 32 + t) << 12) + o * 64 +
                          (((kap >> 3) ^ (o & 7)) << 3) + (kap & 7)] =
                        (_Float16)(acc[s][j][r] + bias[o]);
                }
    }
}

// ---------------- causal flash attention, anti-phase KV split ----------------
// grid (32, 32): x = bh -> XCD = bh%8; y -> p = 31-y (heavy first).
// 512 threads = 8 waves = 2 groups of 4; group g owns KV tiles
// [g?nmax:0, g?p+1:nmax), nmax = ceil((p+1)/2). Private staging per group.
// Group 0: stage(t+1) -> QK(t) -> SM(t) -> PV(t).
// Group 1: PV(t-1) -> stage(K t+1, V t) -> QK(t) -> SM(t); tail PV after loop.
__global__ __launch_bounds__(512, 2) void attn(
    const _Float16* __restrict__ q_ws, const _Float16* __restrict__ kt_ws,
    const _Float16* __restrict__ vt_ws, float* __restrict__ out) {
    __shared__ __align__(16) _Float16 Ks[2][2][4096];     // [group][buf] 32KB
    __shared__ __align__(16) _Float16 VTs[2][2][4096];    // 32KB
    __shared__ __align__(16) _Float16 Ps[8][1024];        // 16KB -> 80KB total

    const int bh = blockIdx.x, b = bh >> 3, h = bh & 7;
    const int p = 31 - blockIdx.y;            // q-half index, heavy first
    const int q0 = p * 64;                    // first q row of this half
    const int nmax = (p + 2) >> 1;            // ceil((p+1)/2) = uniform loop count

    const int bS = b * 2048;
    const int tid = threadIdx.x;
    const int w = tid >> 6, lane = tid & 63, quad = lane >> 4, cl = lane & 15;
    const int g = w >> 2, wl = w & 3;         // group, wave-in-group
    const int tbase = g ? nmax : 0;           // first KV tile of my group
    const int nit = g ? (p + 1 - nmax) : nmax;// my group's iteration count

    const _Float16* kbase = kt_ws + ((size_t)(b * 32) << 12);
    const _Float16* vbase = vt_ws + ((size_t)((b * 8 + h) * 32) << 12);

    const int g0 = (quad ^ (cl & 7)) << 3;
    const int g1 = ((quad ^ 4) ^ (cl & 7)) << 3;
    const int so0 = wl * 1024 + lane * 8;     // group-local staging offset

    // Q pre-scaled by SCL2E in gemm epilogue (both groups load same 64 rows)
    const _Float16* qbase = q_ws + (size_t)(bS + q0 + wl * 16 + cl) * 512 + h * 64;
    half8 qa0 = *(const half8*)(qbase + quad * 8);
    half8 qa1 = *(const half8*)(qbase + 32 + quad * 8);

    float4v oacc[4] = {};
    float l_run[4] = {0.f, 0.f, 0.f, 0.f};

    _Float16* KsG = &Ks[g][0][0];             // my group's [2][4096]
    _Float16* VsG = &VTs[g][0][0];

    auto stageK = [&](int tile, int buf) {
        const _Float16* kt = kbase + ((size_t)tile << 12);
        load16(kt + so0,       KsG + buf * 4096 + wl * 1024);
        load16(kt + so0 + 512, KsG + buf * 4096 + wl * 1024 + 512);
    };
    auto stageV = [&](int tile, int buf) {
        const _Float16* vt = vbase + ((size_t)tile << 12);
        load16(vt + so0,       VsG + buf * 4096 + wl * 1024);
        load16(vt + so0 + 512, VsG + buf * 4096 + wl * 1024 + 512);
    };
    auto qk_sm = [&](int tg, int buf) {
        const _Float16* KB = KsG + buf * 4096;
        if (tg != p) {
            // ---- full tile: maskless fast path ----
            float4v sfr[4];
#pragma unroll
            for (int j = 0; j < 4; ++j) {
                const _Float16* kr = KB + (j * 16 + cl) * 64;
                half8 b0 = *(const half8*)(kr + g0);
                half8 b1 = *(const half8*)(kr + g1);
                float4v a_ = {0.f, 0.f, 0.f, 0.f};
                a_ = mfma16(qa0, b0, a_);
                a_ = mfma16(qa1, b1, a_);
                sfr[j] = a_;
            }
#pragma unroll
            for (int r = 0; r < 4; ++r) {
                float p0 = exp2f(sfr[0][r]), p1 = exp2f(sfr[1][r]);
                float p2 = exp2f(sfr[2][r]), p3 = exp2f(sfr[3][r]);
                l_run[r] += (p0 + p1) + (p2 + p3);
                int rr = quad * 4 + r;
                half4 ph = {(_Float16)p0, (_Float16)p1, (_Float16)p2, (_Float16)p3};
                *(half4*)&Ps[w][rr * 64 + ((((cl >> 1) ^ (rr & 7)) << 3) | ((cl & 1) << 2))] = ph;
            }
        } else {
            // ---- diagonal tile: masked path (sub-block index = wl) ----
            const int jmax = wl;
            float4v sfr[4];
#pragma unroll
            for (int j = 0; j < 4; ++j) {
                if (j <= jmax) {
                    const _Float16* kr = KB + (j * 16 + cl) * 64;
                    half8 b0 = *(const half8*)(kr + g0);
                    half8 b1 = *(const half8*)(kr + g1);
                    float4v a_ = {0.f, 0.f, 0.f, 0.f};
                    a_ = mfma16(qa0, b0, a_);
                    a_ = mfma16(qa1, b1, a_);
                    sfr[j] = a_;
                }
            }
#pragma unroll
            for (int r = 0; r < 4; ++r) {
                float pj[4];
#pragma unroll
                for (int j = 0; j < 4; ++j) {
                    bool live = (j < jmax) || (j == jmax && cl <= quad * 4 + r);
                    pj[j] = live ? exp2f(sfr[j][r]) : 0.f;
                }
                l_run[r] += (pj[0] + pj[1]) + (pj[2] + pj[3]);
                int rr = quad * 4 + r;
                half4 ph = {(_Float16)pj[0], (_Float16)pj[1], (_Float16)pj[2], (_Float16)pj[3]};
                *(half4*)&Ps[w][rr * 64 + ((((cl >> 1) ^ (rr & 7)) << 3) | ((cl & 1) << 2))] = ph;
            }
        }
    };
    auto pv = [&](int buf) {
        // Ps is per-wave: same-wave RAW through LDS, no barrier needed.
        const _Float16* PB = &Ps[w][cl * 64];
        half8 pa0 = *(const half8*)(PB + g0);
        half8 pa1 = *(const half8*)(PB + g1);
        const _Float16* VB = VsG + buf * 4096;
#pragma unroll
        for (int jo = 0; jo < 4; ++jo) {
            const _Float16* vr = VB + (jo * 16 + cl) * 64;
            half8 v0 = *(const half8*)(vr + g0);
            half8 v1 = *(const half8*)(vr + g1);
            oacc[jo] = mfma16(pa0, v0, oacc[jo]);
            oacc[jo] = mfma16(pa1, v1, oacc[jo]);
        }
    };

    // prologue
    if (nit > 0) {
        stageK(tbase, 0);
        if (g == 0) stageV(tbase, 0);   // g1 stages V(t) inside trip t
    }

    for (int t = 0; t < nmax; ++t) {
        const int cb = t & 1, nb = cb ^ 1;
        __syncthreads();   // staged tiles landed (vmcnt drain); buf[nb] reads done
        const int tg = tbase + t;
        if (g == 0) {
            if (t + 1 < nit) { stageK(tg + 1, nb); stageV(tg + 1, nb); }
            qk_sm(tg, cb);
            pv(cb);
        } else {
            if (t > 0 && t - 1 < nit) pv(nb);          // PV of tile tg-1 (V in buf (t-1)&1)
            if (t + 1 < nit) stageK(tg + 1, nb);
            if (t < nit) {
                stageV(tg, cb);                         // V(t): read at trip t+1 / tail
                qk_sm(tg, cb);
            }
        }
    }

    __syncthreads();                              // all staging landed, all LDS reads done
    if (g == 1 && nit == nmax) pv((nmax - 1) & 1);   // tail PV not covered in-loop

    // ---- in-block combine: group 1 -> LDS, group 0 adds + normalizes ----
    float* Obuf = (float*)&Ks[1][0][0];           // 16KB (g1 K staging, dead)
    float* Lbuf = (float*)&VTs[0][0][0];          // 4KB of g0 V staging (dead)
    if (g == 1) {
#pragma unroll
        for (int jo = 0; jo < 4; ++jo)
#pragma unroll
            for (int r = 0; r < 4; ++r) {
                int row = wl * 16 + quad * 4 + r;
                Obuf[row * 64 + jo * 16 + cl] = oacc[jo][r];
            }
#pragma unroll
        for (int r = 0; r < 4; ++r) {
            int row = wl * 16 + quad * 4 + r;
            Lbuf[row * 16 + cl] = l_run[r];
        }
    }
    __syncthreads();
    if (g == 0) {
#pragma unroll
        for (int r = 0; r < 4; ++r) {
            int row = wl * 16 + quad * 4 + r;
            float l = l_run[r] + Lbuf[row * 16 + cl];
            l += __shfl_xor(l, 1);
            l += __shfl_xor(l, 2);
            l += __shfl_xor(l, 4);
            l += __shfl_xor(l, 8);
            float inv = 1.0f / l;
            float* op = out + (size_t)(bS + q0 + row) * 512 + h * 64 + cl;
            op[0]  = (oacc[0][r] + Obuf[row * 64 +      cl]) * inv;
            op[16] = (oacc[1][r] + Obuf[row * 64 + 16 + cl]) * inv;
            op[32] = (oacc[2][r] + Obuf[row * 64 + 32 + cl]) * inv;
            op[48] = (oacc[3][r] + Obuf[row * 64 + 48 + cl]) * inv;
        }
    }
}

extern "C" void kernel_launch(void* const* d_in, const int* in_sizes, int n_in,
                              void* d_out, int out_size, void* d_ws, size_t ws_size,
                              hipStream_t stream) {
    const float* x  = (const float*)d_in[0];
    const float* Wq = (const float*)d_in[1];
    const float* bq = (const float*)d_in[2];
    const float* Wk = (const float*)d_in[3];
    const float* Wv = (const float*)d_in[4];
    const float* bv = (const float*)d_in[5];
    float* out = (float*)d_out;

    char* ws = (char*)d_ws;
    _Float16* q_ws  = (_Float16*)(ws);                 // 8192*512*2     = 8388608
    _Float16* kt_ws = (_Float16*)(ws + 8388608);       // 4*32*4096*2    = 1048576
    _Float16* vt_ws = (_Float16*)(ws + 9437184);       // 4*8*32*4096*2  = 8388608
    _Float16* wqt   = (_Float16*)(ws + 17825792);      // 512*512*2      = 524288
    _Float16* wkt   = (_Float16*)(ws + 18350080);      // 64*512*2       = 65536
    _Float16* wvt   = (_Float16*)(ws + 18415616);      // 512*512*2      = 524288
    _Float16* xh    = (_Float16*)(ws + 18939904);      // 8192*512*2     = 8388608 -> end 27328512

    prep<<<dim3(2592), dim3(256), 0, stream>>>(x, Wq, Wk, Wv, xh, wqt, wkt, wvt);

    qkv_gemm<<<dim3(64, 17), dim3(256), 0, stream>>>(
        xh, wqt, wkt, wvt, bq, bv, q_ws, kt_ws, vt_ws);

    attn<<<dim3(32, 32), dim3(512), 0, stream>>>(q_ws, kt_ws, vt_ws, out);
}